// Round 1
// baseline (2531.840 us; speedup 1.0000x reference)
//
#include <hip/hip_runtime.h>

// ---------------- constants ----------------
#define NV 100000
#define NPAD 100032LL          // 64-row padded
#define CHUNKS 1563            // NPAD/64
#define KVSPLIT 96

typedef __attribute__((ext_vector_type(8))) short bf16x8;
typedef __attribute__((ext_vector_type(4))) float f32x4;

constexpr size_t SB      = (size_t)NPAD * 256 * 2;        // one [NPAD,256] bf16 buffer
constexpr size_t OFF_XB  = 0;                             // x bf16; later reused as h1
constexpr size_t OFF_H0  = SB;
constexpr size_t OFF_Q   = 2 * SB;
constexpr size_t OFF_KT  = 3 * SB;                        // [256][NPAD]
constexpr size_t OFF_VT  = 4 * SB;                        // [256][NPAD]
constexpr size_t OFF_WB  = 5 * SB;                        // 7 x 65536 bf16 weights
constexpr size_t OFF_KVB = OFF_WB + (size_t)7 * 65536 * 2;// KVT bf16 [256][256]
constexpr size_t OFF_RED = OFF_KVB + (size_t)65536 * 2;   // 2 layers x REDL floats
constexpr int    REDL    = 66048;  // per-layer: [0]=q_ss [1]=k_ss [16..271]=ksum [512..66047]=KVT_acc
constexpr size_t OFF_KS  = OFF_RED + (size_t)2 * REDL * 4; // ksum_scaled [256] f32

// ---------------- helpers ----------------
__device__ __forceinline__ float b2f(unsigned short h) {
  unsigned u = ((unsigned)h) << 16;
  return __builtin_bit_cast(float, u);
}
__device__ __forceinline__ unsigned short f2bf(float x) {
  unsigned u = __builtin_bit_cast(unsigned, x);
  u = (u + 0x7fffu + ((u >> 16) & 1u)) >> 16;
  return (unsigned short)u;
}
__device__ __forceinline__ void async16(void* lds, const void* g) {
  __builtin_amdgcn_global_load_lds((const __attribute__((address_space(1))) unsigned*)g,
                                   (__attribute__((address_space(3))) unsigned*)lds,
                                   16, 0, 0);
}

// ---------------- zero / convert ----------------
__global__ void k_zero(char* ws) {
  int i = blockIdx.x * 256 + threadIdx.x;
  if (i < 2 * REDL) {
    ((float*)(ws + OFF_RED))[i] = 0.0f;
  } else {
    int p = i - 2 * REDL;
    if (p < 8192) {               // zero kT/vT pad columns n in [NV, NPAD)
      int buf = p >> 12;
      int r = p & 4095;
      int row = r >> 4, word = r & 15;
      unsigned* b = (unsigned*)(ws + (buf ? OFF_VT : OFF_KT));
      b[(size_t)row * (NPAD / 2) + (NV / 2) + word] = 0u;
    }
  }
}

__global__ void k_conv(const float* __restrict__ x, const float* __restrict__ fcw,
                       const float* __restrict__ wq, const float* __restrict__ wk,
                       const float* __restrict__ wv, char* __restrict__ ws) {
  long long t = (long long)blockIdx.x * 256 + threadIdx.x;
  if (t < 6400000LL) {            // x -> bf16
    float4 v = ((const float4*)x)[t];
    unsigned lo = (unsigned)f2bf(v.x) | ((unsigned)f2bf(v.y) << 16);
    unsigned hi = (unsigned)f2bf(v.z) | ((unsigned)f2bf(v.w) << 16);
    ((uint2*)(ws + OFF_XB))[t] = make_uint2(lo, hi);
  } else {
    long long u = t - 6400000LL;
    if (u < 114688LL) {           // weights -> bf16, slots [fc, q0,k0,v0, q1,k1,v1]
      int e4 = (int)(u << 2);
      int slot = e4 >> 16, within = e4 & 65535;
      const float* src;
      if (slot == 0) src = fcw + within;
      else {
        int s = slot - 1, l = s / 3, k = s % 3;
        src = (k == 0 ? wq : (k == 1 ? wk : wv)) + l * 65536 + within;
      }
      float4 v = *(const float4*)src;
      unsigned lo = (unsigned)f2bf(v.x) | ((unsigned)f2bf(v.y) << 16);
      unsigned hi = (unsigned)f2bf(v.z) | ((unsigned)f2bf(v.w) << 16);
      ((uint2*)(ws + OFF_WB))[u] = make_uint2(lo, hi);
    }
  }
}

// ---------------- main fused GEMM (64 rows x 256 cols, K=256) ----------------
// modes: 0 fc(bias+LN+relu->bf16)  100 qkv (z: 1=q,2=k,3=v)
//        4 pass2 mid (attn+mix+LN+relu->bf16)  5 pass2 final (->f32)
__global__ __launch_bounds__(256) void gemm64(
    const unsigned short* __restrict__ A,
    const unsigned short* __restrict__ B0,
    const float* __restrict__ biasQ, const float* __restrict__ biasK,
    const float* __restrict__ biasV,
    const float* __restrict__ lng, const float* __restrict__ lnb,
    unsigned short* __restrict__ outN,
    unsigned short* __restrict__ outKT, unsigned short* __restrict__ outVT,
    float* __restrict__ outF,
    const unsigned short* __restrict__ vT, const unsigned short* __restrict__ prevH,
    const float* __restrict__ ksumS,
    float* __restrict__ red, int mode) {
  __shared__ uint4 sA[512];    // 64 x 64 bf16 (xor-swizzled 16B granules)
  __shared__ uint4 sB[2048];   // 256 x 64 bf16
  __shared__ float sLNs[256], sLNq[256], sM[64], sR[64], sRDp[256], sRDt[64], sSS[4];

  const int tid = threadIdx.x;
  const int w = tid >> 6, lane = tid & 63, quad = lane >> 4, lc = lane & 15;
  const int c0 = w * 64;
  const long long n0 = (long long)blockIdx.x * 64;

  const int am = (mode == 100) ? 1 + blockIdx.z : mode;
  const unsigned short* Bm = (mode == 100) ? B0 + (size_t)blockIdx.z * 65536 : B0;

  f32x4 acc[4][4];
  for (int i = 0; i < 4; ++i)
    for (int j = 0; j < 4; ++j) acc[i][j] = (f32x4){0.f, 0.f, 0.f, 0.f};

  float rd_part = 0.f;

  for (int kc = 0; kc < 4; ++kc) {
    const int kc_off = kc * 64;
    // stage A (64x64): 2 granules/thread
    for (int it = 0; it < 2; ++it) {
      int s = it * 256 + tid;
      int m = s >> 3, gc = s & 7, gsrc = gc ^ (m & 7);
      async16(&sA[s], A + (size_t)(n0 + m) * 256 + kc_off + gsrc * 8);
    }
    // stage B (256x64): 8 granules/thread
    for (int it = 0; it < 8; ++it) {
      int s = it * 256 + tid;
      int j = s >> 3, gc = s & 7, gsrc = gc ^ (j & 7);
      async16(&sB[s], Bm + (size_t)j * 256 + kc_off + gsrc * 8);
    }
    __syncthreads();

    if (am >= 4) {  // rowdot partial: q . ksum_scaled
      const int row = tid >> 2, p = tid & 3;
      for (int gg = 0; gg < 2; ++gg) {
        int g = p * 2 + gg;
        uint4 gr = sA[row * 8 + (g ^ (row & 7))];
        unsigned uu[4] = {gr.x, gr.y, gr.z, gr.w};
        for (int h = 0; h < 4; ++h) {
          rd_part += b2f((unsigned short)(uu[h] & 0xffffu)) * ksumS[kc_off + g * 8 + h * 2];
          rd_part += b2f((unsigned short)(uu[h] >> 16))     * ksumS[kc_off + g * 8 + h * 2 + 1];
        }
      }
    }

    for (int kk = 0; kk < 2; ++kk) {
      bf16x8 af[4], bf[4];
      for (int fr = 0; fr < 4; ++fr) {
        int m = fr * 16 + lc;
        af[fr] = __builtin_bit_cast(bf16x8, sA[m * 8 + ((kk * 4 + quad) ^ (m & 7))]);
      }
      for (int fc = 0; fc < 4; ++fc) {
        int j = c0 + fc * 16 + lc;
        bf[fc] = __builtin_bit_cast(bf16x8, sB[j * 8 + ((kk * 4 + quad) ^ (j & 7))]);
      }
      for (int fr = 0; fr < 4; ++fr)
        for (int fc = 0; fc < 4; ++fc)
          acc[fr][fc] = __builtin_amdgcn_mfma_f32_16x16x32_bf16(af[fr], bf[fc], acc[fr][fc], 0, 0, 0);
    }
    __syncthreads();
  }

  // ---------------- epilogues ----------------
  if (am == 0 || am >= 4) {
    const bool isAttn = (am >= 4);
    if (isAttn) sRDp[tid] = rd_part;
    __syncthreads();
    if (isAttn && tid < 64)
      sRDt[tid] = sRDp[tid * 4] + sRDp[tid * 4 + 1] + sRDp[tid * 4 + 2] + sRDp[tid * 4 + 3];
    if (isAttn) __syncthreads();

    float gv[4], bbv[4], bq[4];
    for (int fc = 0; fc < 4; ++fc) {
      int j = c0 + fc * 16 + lc;
      gv[fc] = lng[j]; bbv[fc] = lnb[j];
      bq[fc] = (am == 0) ? biasQ[j] : 0.f;
    }

    for (int fr = 0; fr < 4; ++fr) {
      long long nb = n0 + fr * 16 + quad * 4;
      int rrb = fr * 16 + quad * 4;
      float s1[4] = {0, 0, 0, 0}, s2[4] = {0, 0, 0, 0};
      for (int fc = 0; fc < 4; ++fc) {
        int j = c0 + fc * 16 + lc;
        float vload[4];
        if (isAttn) {
          uint2 vv = *(const uint2*)(vT + (size_t)j * NPAD + nb);
          vload[0] = b2f((unsigned short)(vv.x & 0xffffu));
          vload[1] = b2f((unsigned short)(vv.x >> 16));
          vload[2] = b2f((unsigned short)(vv.y & 0xffffu));
          vload[3] = b2f((unsigned short)(vv.y >> 16));
        }
        for (int r = 0; r < 4; ++r) {
          float v = acc[fr][fc][r];
          if (isAttn) {
            float rd = sRDt[rrb + r];
            float at = (v + 100000.0f * vload[r]) / (rd + 100000.0f);
            float pv = b2f(prevH[(size_t)(nb + r) * 256 + j]);
            v = 0.5f * at + 0.5f * pv;
          } else {
            v += bq[fc];
          }
          acc[fr][fc][r] = v;
          s1[r] += v; s2[r] += v * v;
        }
      }
      for (int r = 0; r < 4; ++r) {
        float a = s1[r], b = s2[r];
        a += __shfl_xor(a, 1); b += __shfl_xor(b, 1);
        a += __shfl_xor(a, 2); b += __shfl_xor(b, 2);
        a += __shfl_xor(a, 4); b += __shfl_xor(b, 4);
        a += __shfl_xor(a, 8); b += __shfl_xor(b, 8);
        if (lc == 0) { sLNs[w * 64 + rrb + r] = a; sLNq[w * 64 + rrb + r] = b; }
      }
    }
    __syncthreads();
    if (tid < 64) {
      float S = sLNs[tid] + sLNs[64 + tid] + sLNs[128 + tid] + sLNs[192 + tid];
      float Q = sLNq[tid] + sLNq[64 + tid] + sLNq[128 + tid] + sLNq[192 + tid];
      float mean = S * (1.f / 256.f);
      float var = Q * (1.f / 256.f) - mean * mean;
      sM[tid] = mean; sR[tid] = rsqrtf(var + 1e-5f);
    }
    __syncthreads();
    for (int fr = 0; fr < 4; ++fr) {
      long long nb = n0 + fr * 16 + quad * 4;
      int rrb = fr * 16 + quad * 4;
      for (int fc = 0; fc < 4; ++fc) {
        int j = c0 + fc * 16 + lc;
        for (int r = 0; r < 4; ++r) {
          long long n = nb + r;
          float y = (acc[fr][fc][r] - sM[rrb + r]) * sR[rrb + r] * gv[fc] + bbv[fc];
          y = fmaxf(y, 0.f);
          if (n < NV) {
            if (am == 5) outF[(size_t)n * 256 + j] = y;
            else         outN[(size_t)n * 256 + j] = f2bf(y);
          }
        }
      }
    }
  } else {
    // qkv epilogue (am 1/2/3)
    const float* bias = (am == 1) ? biasQ : (am == 2) ? biasK : biasV;
    float bq[4], cs[4] = {0, 0, 0, 0};
    for (int fc = 0; fc < 4; ++fc) bq[fc] = bias[c0 + fc * 16 + lc];
    float ss = 0.f;
    for (int fr = 0; fr < 4; ++fr) {
      long long nb = n0 + fr * 16 + quad * 4;
      for (int fc = 0; fc < 4; ++fc) {
        int j = c0 + fc * 16 + lc;
        float vals[4];
        for (int r = 0; r < 4; ++r) {
          float v = acc[fr][fc][r] + bq[fc];
          vals[r] = v;
          bool ok = (nb + r) < NV;
          if (am != 3 && ok) ss += v * v;
          if (am == 2 && ok) cs[fc] += v;
        }
        if (am == 1) {
          for (int r = 0; r < 4; ++r)
            if (nb + r < NV) outN[(size_t)(nb + r) * 256 + j] = f2bf(vals[r]);
        } else {
          if (nb < NV) {  // transposed bf16 store: 4 consecutive n -> 8B
            unsigned p0 = (unsigned)f2bf(vals[0]) | ((unsigned)f2bf(vals[1]) << 16);
            unsigned p1 = (unsigned)f2bf(vals[2]) | ((unsigned)f2bf(vals[3]) << 16);
            unsigned short* outT = (am == 2) ? outKT : outVT;
            *(uint2*)(outT + (size_t)j * NPAD + nb) = make_uint2(p0, p1);
          }
        }
      }
    }
    if (am != 3) {
      for (int msk = 1; msk <= 32; msk <<= 1) ss += __shfl_xor(ss, msk);
      if (lane == 0) sSS[w] = ss;
    }
    if (am == 2) {
      for (int fc = 0; fc < 4; ++fc) {
        float c = cs[fc];
        c += __shfl_xor(c, 16);
        c += __shfl_xor(c, 32);
        if (quad == 0) atomicAdd(&red[16 + c0 + fc * 16 + lc], c);
      }
    }
    __syncthreads();
    if (am != 3 && tid == 0)
      atomicAdd(&red[am == 1 ? 0 : 1], sSS[0] + sSS[1] + sSS[2] + sSS[3]);
  }
}

// ---------------- KV = k^T v, split-K, atomic accumulate into KV^T (f32) ----------------
__global__ __launch_bounds__(256) void kvker(const unsigned short* __restrict__ kT,
                                             const unsigned short* __restrict__ vT,
                                             float* __restrict__ accT) {
  __shared__ uint4 sA[1024];   // 128 x 64 bf16 (k^T rows m)
  __shared__ uint4 sB[1024];   // 128 x 64 bf16 (v^T rows d)
  const int tid = threadIdx.x;
  const int w = tid >> 6, lane = tid & 63, quad = lane >> 4, lc = lane & 15;
  const int tm = (blockIdx.y & 1) * 128, td = (blockIdx.y >> 1) * 128;
  const int m0w = (w & 1) * 64, d0w = (w >> 1) * 64;

  f32x4 acc[4][4];
  for (int i = 0; i < 4; ++i)
    for (int j = 0; j < 4; ++j) acc[i][j] = (f32x4){0.f, 0.f, 0.f, 0.f};

  for (int c = blockIdx.x; c < CHUNKS; c += KVSPLIT) {
    const long long noff = (long long)c * 64;
    for (int it = 0; it < 4; ++it) {
      int s = it * 256 + tid;
      int mloc = s >> 3, gc = s & 7, gsrc = gc ^ (mloc & 7);
      async16(&sA[s], kT + (size_t)(tm + mloc) * NPAD + noff + gsrc * 8);
      async16(&sB[s], vT + (size_t)(td + mloc) * NPAD + noff + gsrc * 8);
    }
    __syncthreads();
    for (int kk = 0; kk < 2; ++kk) {
      bf16x8 af[4], bf[4];
      for (int fr = 0; fr < 4; ++fr) {
        int m = m0w + fr * 16 + lc;
        af[fr] = __builtin_bit_cast(bf16x8, sA[m * 8 + ((kk * 4 + quad) ^ (m & 7))]);
      }
      for (int fc = 0; fc < 4; ++fc) {
        int d = d0w + fc * 16 + lc;
        bf[fc] = __builtin_bit_cast(bf16x8, sB[d * 8 + ((kk * 4 + quad) ^ (d & 7))]);
      }
      for (int fr = 0; fr < 4; ++fr)
        for (int fc = 0; fc < 4; ++fc)
          acc[fr][fc] = __builtin_amdgcn_mfma_f32_16x16x32_bf16(af[fr], bf[fc], acc[fr][fc], 0, 0, 0);
    }
    __syncthreads();
  }
  for (int fr = 0; fr < 4; ++fr) {
    int m = tm + m0w + fr * 16 + quad * 4;
    for (int fc = 0; fc < 4; ++fc) {
      int d = td + d0w + fc * 16 + lc;
      for (int r = 0; r < 4; ++r)
        atomicAdd(&accT[(size_t)d * 256 + m + r], acc[fr][fc][r]);
    }
  }
}

// ---------------- finalize: scale KV^T by gamma, emit bf16; scale ksum ----------------
__global__ void k_fin(const float* __restrict__ red, unsigned short* __restrict__ kvb,
                      float* __restrict__ ksums) {
  float g = rsqrtf(red[0]) * rsqrtf(red[1]);   // 1/(||q|| * ||k||)
  if (blockIdx.x < 256) {
    int i = blockIdx.x * 256 + threadIdx.x;
    kvb[i] = f2bf(red[512 + i] * g);
  } else {
    ksums[threadIdx.x] = red[16 + threadIdx.x] * g;
  }
}

// ---------------- launch ----------------
extern "C" void kernel_launch(void* const* d_in, const int* in_sizes, int n_in,
                              void* d_out, int out_size, void* d_ws, size_t ws_size,
                              hipStream_t stream) {
  const float* x   = (const float*)d_in[0];
  const float* fcw = (const float*)d_in[1];
  const float* fcb = (const float*)d_in[2];
  const float* wqw = (const float*)d_in[3];
  const float* wqb = (const float*)d_in[4];
  const float* wkw = (const float*)d_in[5];
  const float* wkb = (const float*)d_in[6];
  const float* wvw = (const float*)d_in[7];
  const float* wvb = (const float*)d_in[8];
  const float* lng = (const float*)d_in[9];
  const float* lnb = (const float*)d_in[10];
  char* ws = (char*)d_ws;
  float* out = (float*)d_out;

  unsigned short* xb  = (unsigned short*)(ws + OFF_XB);
  unsigned short* h0  = (unsigned short*)(ws + OFF_H0);
  unsigned short* h1  = xb;  // x dead after fc kernel -> reuse as h1
  unsigned short* q   = (unsigned short*)(ws + OFF_Q);
  unsigned short* kT  = (unsigned short*)(ws + OFF_KT);
  unsigned short* vT  = (unsigned short*)(ws + OFF_VT);
  unsigned short* wb  = (unsigned short*)(ws + OFF_WB);
  unsigned short* kvb = (unsigned short*)(ws + OFF_KVB);
  float* ksums = (float*)(ws + OFF_KS);

  k_zero<<<548, 256, 0, stream>>>(ws);
  k_conv<<<25448, 256, 0, stream>>>(x, fcw, wqw, wkw, wvw, ws);

  // fc: h0 = relu(LN(x @ fc_w^T + fc_b))
  gemm64<<<dim3(1563, 1, 1), 256, 0, stream>>>(
      xb, wb, fcb, nullptr, nullptr, lng, lnb,
      h0, nullptr, nullptr, nullptr, nullptr, nullptr, nullptr, nullptr, 0);

  for (int l = 0; l < 2; ++l) {
    unsigned short* hin  = (l == 0) ? h0 : h1;
    unsigned short* hout = (l == 0) ? h1 : nullptr;
    float* red = (float*)(ws + OFF_RED) + (size_t)l * REDL;

    // q,k,v + reductions (z: 0=q,1=k,2=v)
    gemm64<<<dim3(1563, 1, 3), 256, 0, stream>>>(
        hin, wb + (size_t)(1 + 3 * l) * 65536,
        wqb + l * 256, wkb + l * 256, wvb + l * 256, nullptr, nullptr,
        q, kT, vT, nullptr, nullptr, nullptr, nullptr, red, 100);

    kvker<<<dim3(KVSPLIT, 4, 1), 256, 0, stream>>>(kT, vT, red + 512);
    k_fin<<<257, 256, 0, stream>>>(red, kvb, ksums);

    // pass2: attn + mix + LN + relu
    gemm64<<<dim3(1563, 1, 1), 256, 0, stream>>>(
        q, kvb, nullptr, nullptr, nullptr,
        lng + (size_t)(l + 1) * 256, lnb + (size_t)(l + 1) * 256,
        hout, nullptr, nullptr, (l == 1) ? out : nullptr,
        vT, hin, ksums, red, 4 + l);
  }
}

// Round 2
// 2263.228 us; speedup vs baseline: 1.1187x; 1.1187x over previous
//
#include <hip/hip_runtime.h>

// ---------------- constants ----------------
#define NV 100000
#define NPAD 100032LL          // 64-row padded
#define CHUNKS 1563            // NPAD/64
#define KVSPLIT 128

typedef __attribute__((ext_vector_type(8))) short bf16x8;
typedef __attribute__((ext_vector_type(4))) float f32x4;

constexpr size_t SB      = (size_t)NPAD * 256 * 2;        // one [NPAD,256] bf16 buffer
constexpr size_t OFF_XB  = 0;                             // x bf16; later reused as h1
constexpr size_t OFF_H0  = SB;
constexpr size_t OFF_Q   = 2 * SB;
constexpr size_t OFF_KT  = 3 * SB;                        // [256][NPAD]
constexpr size_t OFF_VT  = 4 * SB;                        // [256][NPAD]
constexpr size_t OFF_WB  = 5 * SB;                        // 7 x 65536 bf16 weights
constexpr size_t OFF_KVB = OFF_WB + (size_t)7 * 65536 * 2;// KVT bf16 [256][256]
constexpr int    REDL    = 512;  // per-layer: [0]=q_ss [1]=k_ss [16..271]=ksum
constexpr size_t OFF_RED = OFF_KVB + (size_t)65536 * 2;
constexpr size_t OFF_KS  = OFF_RED + (size_t)2 * REDL * 4; // ksum_scaled [256] f32

// ---------------- helpers ----------------
__device__ __forceinline__ float b2f(unsigned short h) {
  unsigned u = ((unsigned)h) << 16;
  return __builtin_bit_cast(float, u);
}
__device__ __forceinline__ unsigned short f2bf(float x) {
  unsigned u = __builtin_bit_cast(unsigned, x);
  u = (u + 0x7fffu + ((u >> 16) & 1u)) >> 16;
  return (unsigned short)u;
}
__device__ __forceinline__ void async16(void* lds, const void* g) {
  __builtin_amdgcn_global_load_lds((const __attribute__((address_space(1))) unsigned*)g,
                                   (__attribute__((address_space(3))) unsigned*)lds,
                                   16, 0, 0);
}

// ---------------- zero reductions ----------------
__global__ void k_zero(char* ws) {
  int i = blockIdx.x * 256 + threadIdx.x;
  if (i < 2 * REDL) ((float*)(ws + OFF_RED))[i] = 0.0f;
}

__global__ void k_conv(const float* __restrict__ x, const float* __restrict__ fcw,
                       const float* __restrict__ wq, const float* __restrict__ wk,
                       const float* __restrict__ wv, char* __restrict__ ws) {
  long long t = (long long)blockIdx.x * 256 + threadIdx.x;
  if (t < 6400000LL) {            // x -> bf16
    float4 v = ((const float4*)x)[t];
    unsigned lo = (unsigned)f2bf(v.x) | ((unsigned)f2bf(v.y) << 16);
    unsigned hi = (unsigned)f2bf(v.z) | ((unsigned)f2bf(v.w) << 16);
    ((uint2*)(ws + OFF_XB))[t] = make_uint2(lo, hi);
  } else {
    long long u = t - 6400000LL;
    if (u < 114688LL) {           // weights -> bf16, slots [fc, q0,k0,v0, q1,k1,v1]
      int e4 = (int)(u << 2);
      int slot = e4 >> 16, within = e4 & 65535;
      const float* src;
      if (slot == 0) src = fcw + within;
      else {
        int s = slot - 1, l = s / 3, k = s % 3;
        src = (k == 0 ? wq : (k == 1 ? wk : wv)) + l * 65536 + within;
      }
      float4 v = *(const float4*)src;
      unsigned lo = (unsigned)f2bf(v.x) | ((unsigned)f2bf(v.y) << 16);
      unsigned hi = (unsigned)f2bf(v.z) | ((unsigned)f2bf(v.w) << 16);
      ((uint2*)(ws + OFF_WB))[u] = make_uint2(lo, hi);
    }
  }
}

// ---------------- main fused GEMM (64 rows x 256 cols, K=256) ----------------
// modes: 0 fc(bias+LN+relu->bf16)  100 qkv (z: 1=q,2=k,3=v)
//        4 pass2 mid (attn+mix+LN+relu->bf16)  5 pass2 final (->f32)
__global__ __launch_bounds__(256) void gemm64(
    const unsigned short* __restrict__ A,
    const unsigned short* __restrict__ B0,
    const float* __restrict__ biasQ, const float* __restrict__ biasK,
    const float* __restrict__ biasV,
    const float* __restrict__ lng, const float* __restrict__ lnb,
    unsigned short* __restrict__ outN,
    unsigned short* __restrict__ outKT, unsigned short* __restrict__ outVT,
    float* __restrict__ outF,
    const unsigned short* __restrict__ vT, const unsigned short* __restrict__ prevH,
    const float* __restrict__ ksumS,
    float* __restrict__ red, int mode) {
  __shared__ uint4 smem4[2816];                 // 44 KiB
  uint4* sA = smem4;                            // [512]  64 x 64 bf16 (xor-swizzled)
  uint4* sB = smem4 + 512;                      // [2048] 256 x 64 bf16
  float* sLNs = (float*)smem4 + 10240;          // 256
  float* sLNq = (float*)smem4 + 10496;          // 256
  float* sM   = (float*)smem4 + 10752;          // 64
  float* sR   = (float*)smem4 + 10816;          // 64
  float* sRDp = (float*)smem4 + 10880;          // 256
  float* sRDt = (float*)smem4 + 11136;          // 64
  float* sSS  = (float*)smem4 + 11200;          // 4

  const int tid = threadIdx.x;
  const int w = tid >> 6, lane = tid & 63, quad = lane >> 4, lc = lane & 15;
  const int c0 = w * 64;
  const long long n0 = (long long)blockIdx.x * 64;

  const int am = (mode == 100) ? 1 + blockIdx.z : mode;
  const unsigned short* Bm = (mode == 100) ? B0 + (size_t)blockIdx.z * 65536 : B0;

  f32x4 acc[4][4];
  for (int i = 0; i < 4; ++i)
    for (int j = 0; j < 4; ++j) acc[i][j] = (f32x4){0.f, 0.f, 0.f, 0.f};

  float rd_part = 0.f;

  for (int kc = 0; kc < 4; ++kc) {
    const int kc_off = kc * 64;
    for (int it = 0; it < 2; ++it) {            // stage A (64x64)
      int s = it * 256 + tid;
      int m = s >> 3, gc = s & 7, gsrc = gc ^ (m & 7);
      async16(&sA[s], A + (size_t)(n0 + m) * 256 + kc_off + gsrc * 8);
    }
    for (int it = 0; it < 8; ++it) {            // stage B (256x64)
      int s = it * 256 + tid;
      int j = s >> 3, gc = s & 7, gsrc = gc ^ (j & 7);
      async16(&sB[s], Bm + (size_t)j * 256 + kc_off + gsrc * 8);
    }
    __syncthreads();

    if (am >= 4) {  // rowdot partial: q . ksum_scaled
      const int row = tid >> 2, p = tid & 3;
      for (int gg = 0; gg < 2; ++gg) {
        int g = p * 2 + gg;
        uint4 gr = sA[row * 8 + (g ^ (row & 7))];
        unsigned uu[4] = {gr.x, gr.y, gr.z, gr.w};
        for (int h = 0; h < 4; ++h) {
          rd_part += b2f((unsigned short)(uu[h] & 0xffffu)) * ksumS[kc_off + g * 8 + h * 2];
          rd_part += b2f((unsigned short)(uu[h] >> 16))     * ksumS[kc_off + g * 8 + h * 2 + 1];
        }
      }
    }

    for (int kk = 0; kk < 2; ++kk) {
      bf16x8 af[4], bf[4];
      for (int fr = 0; fr < 4; ++fr) {
        int m = fr * 16 + lc;
        af[fr] = __builtin_bit_cast(bf16x8, sA[m * 8 + ((kk * 4 + quad) ^ (m & 7))]);
      }
      for (int fc = 0; fc < 4; ++fc) {
        int j = c0 + fc * 16 + lc;
        bf[fc] = __builtin_bit_cast(bf16x8, sB[j * 8 + ((kk * 4 + quad) ^ (j & 7))]);
      }
      for (int fr = 0; fr < 4; ++fr)
        for (int fc = 0; fc < 4; ++fc)
          acc[fr][fc] = __builtin_amdgcn_mfma_f32_16x16x32_bf16(af[fr], bf[fc], acc[fr][fc], 0, 0, 0);
    }
    __syncthreads();
  }

  // ---------------- epilogues ----------------
  if (am == 2 || am == 3) {
    // k/v: LDS-transpose then full-line-per-lane transposed store to [256][NPAD]
    const float* bias = (am == 2) ? biasK : biasV;
    float bq[4];
    for (int fc = 0; fc < 4; ++fc) bq[fc] = bias[c0 + fc * 16 + lc];
    unsigned short* sT = (unsigned short*)smem4;   // rows: 72 shorts (144B, 16B-aligned)
    float ss = 0.f, cs[4] = {0, 0, 0, 0};
    for (int fr = 0; fr < 4; ++fr) {
      int nl = fr * 16 + quad * 4;
      long long nb = n0 + nl;
      for (int fc = 0; fc < 4; ++fc) {
        int j = c0 + fc * 16 + lc;
        unsigned short h[4];
        for (int r = 0; r < 4; ++r) {
          float v = acc[fr][fc][r] + bq[fc];
          if (nb + r >= NV) v = 0.f;             // zero pads (kvker relies on this)
          if (am == 2) { ss += v * v; cs[fc] += v; }
          h[r] = f2bf(v);
        }
        *(uint2*)(sT + (size_t)j * 72 + nl) =
            make_uint2((unsigned)h[0] | ((unsigned)h[1] << 16),
                       (unsigned)h[2] | ((unsigned)h[3] << 16));
      }
    }
    if (am == 2) {
      for (int msk = 1; msk <= 32; msk <<= 1) ss += __shfl_xor(ss, msk);
      if (lane == 0) sSS[w] = ss;
      for (int fc = 0; fc < 4; ++fc) {
        float c = cs[fc];
        c += __shfl_xor(c, 16);
        c += __shfl_xor(c, 32);
        if (quad == 0) atomicAdd(&red[16 + c0 + fc * 16 + lc], c);
      }
    }
    __syncthreads();
    {
      unsigned short* outT = (am == 2) ? outKT : outVT;
      const uint4* src = (const uint4*)(sT + (size_t)tid * 72);
      uint4* dst = (uint4*)(outT + (size_t)tid * NPAD + n0);
#pragma unroll
      for (int i = 0; i < 8; ++i) dst[i] = src[i];  // 128B contiguous per lane
    }
    if (am == 2 && tid == 0)
      atomicAdd(&red[1], sSS[0] + sSS[1] + sSS[2] + sSS[3]);
  } else if (am == 1) {
    // q: bias + store [N,256] + ||q||^2 reduction
    float bq[4];
    for (int fc = 0; fc < 4; ++fc) bq[fc] = biasQ[c0 + fc * 16 + lc];
    float ss = 0.f;
    for (int fr = 0; fr < 4; ++fr) {
      long long nb = n0 + fr * 16 + quad * 4;
      for (int fc = 0; fc < 4; ++fc) {
        int j = c0 + fc * 16 + lc;
        for (int r = 0; r < 4; ++r) {
          float v = acc[fr][fc][r] + bq[fc];
          if (nb + r >= NV) v = 0.f;
          ss += v * v;
          if (nb + r < NV) outN[(size_t)(nb + r) * 256 + j] = f2bf(v);
        }
      }
    }
    for (int msk = 1; msk <= 32; msk <<= 1) ss += __shfl_xor(ss, msk);
    if (lane == 0) sSS[w] = ss;
    __syncthreads();
    if (tid == 0) atomicAdd(&red[0], sSS[0] + sSS[1] + sSS[2] + sSS[3]);
  } else {
    // am==0 (fc) or am>=4 (attn): bias/attn + mix + LN + relu
    const bool isAttn = (am >= 4);
    if (isAttn) {
      // stage vT tile [256 j][64 n] into sB (dead after K-loop), swizzled like B
      for (int it = 0; it < 8; ++it) {
        int s = it * 256 + tid;
        int j = s >> 3, gc = s & 7, gsrc = gc ^ (j & 7);
        async16(&sB[s], vT + (size_t)j * NPAD + n0 + gsrc * 8);
      }
      sRDp[tid] = rd_part;
    }
    __syncthreads();   // drains async16 + sRDp visible
    if (isAttn && tid < 64)
      sRDt[tid] = sRDp[tid * 4] + sRDp[tid * 4 + 1] + sRDp[tid * 4 + 2] + sRDp[tid * 4 + 3];
    __syncthreads();

    float gv[4], bbv[4], bq[4];
    for (int fc = 0; fc < 4; ++fc) {
      int j = c0 + fc * 16 + lc;
      gv[fc] = lng[j]; bbv[fc] = lnb[j];
      bq[fc] = (am == 0) ? biasQ[j] : 0.f;
    }

    for (int fr = 0; fr < 4; ++fr) {
      long long nb = n0 + fr * 16 + quad * 4;
      int rrb = fr * 16 + quad * 4;
      float s1[4] = {0, 0, 0, 0}, s2[4] = {0, 0, 0, 0};
      for (int fc = 0; fc < 4; ++fc) {
        int j = c0 + fc * 16 + lc;
        float vload[4];
        if (isAttn) {
          int G = fr * 2 + (quad >> 1);
          const unsigned short* vp =
              (const unsigned short*)&sB[(size_t)j * 8 + (G ^ (j & 7))] + (quad & 1) * 4;
          uint2 vv = *(const uint2*)vp;
          vload[0] = b2f((unsigned short)(vv.x & 0xffffu));
          vload[1] = b2f((unsigned short)(vv.x >> 16));
          vload[2] = b2f((unsigned short)(vv.y & 0xffffu));
          vload[3] = b2f((unsigned short)(vv.y >> 16));
        }
        for (int r = 0; r < 4; ++r) {
          float v = acc[fr][fc][r];
          if (isAttn) {
            float rd = sRDt[rrb + r];
            float at = (v + 100000.0f * vload[r]) / (rd + 100000.0f);
            float pv = b2f(prevH[(size_t)(nb + r) * 256 + j]);
            v = 0.5f * at + 0.5f * pv;
          } else {
            v += bq[fc];
          }
          acc[fr][fc][r] = v;
          s1[r] += v; s2[r] += v * v;
        }
      }
      for (int r = 0; r < 4; ++r) {
        float a = s1[r], b = s2[r];
        a += __shfl_xor(a, 1); b += __shfl_xor(b, 1);
        a += __shfl_xor(a, 2); b += __shfl_xor(b, 2);
        a += __shfl_xor(a, 4); b += __shfl_xor(b, 4);
        a += __shfl_xor(a, 8); b += __shfl_xor(b, 8);
        if (lc == 0) { sLNs[w * 64 + rrb + r] = a; sLNq[w * 64 + rrb + r] = b; }
      }
    }
    __syncthreads();
    if (tid < 64) {
      float S = sLNs[tid] + sLNs[64 + tid] + sLNs[128 + tid] + sLNs[192 + tid];
      float Q = sLNq[tid] + sLNq[64 + tid] + sLNq[128 + tid] + sLNq[192 + tid];
      float mean = S * (1.f / 256.f);
      float var = Q * (1.f / 256.f) - mean * mean;
      sM[tid] = mean; sR[tid] = rsqrtf(var + 1e-5f);
    }
    __syncthreads();
    for (int fr = 0; fr < 4; ++fr) {
      long long nb = n0 + fr * 16 + quad * 4;
      int rrb = fr * 16 + quad * 4;
      for (int fc = 0; fc < 4; ++fc) {
        int j = c0 + fc * 16 + lc;
        for (int r = 0; r < 4; ++r) {
          long long n = nb + r;
          float y = (acc[fr][fc][r] - sM[rrb + r]) * sR[rrb + r] * gv[fc] + bbv[fc];
          y = fmaxf(y, 0.f);
          if (n < NV) {
            if (am == 5) outF[(size_t)n * 256 + j] = y;
            else         outN[(size_t)n * 256 + j] = f2bf(y);
          }
        }
      }
    }
  }
}

// ---------------- KV = k^T v, split-K, per-split f32 partials (no atomics) ------
__global__ __launch_bounds__(256) void kvker(const unsigned short* __restrict__ kT,
                                             const unsigned short* __restrict__ vT,
                                             float* __restrict__ part) {
  __shared__ uint4 sA[1024];   // 128 x 64 bf16 (k^T rows m)
  __shared__ uint4 sB[1024];   // 128 x 64 bf16 (v^T rows d)
  const int tid = threadIdx.x;
  const int w = tid >> 6, lane = tid & 63, quad = lane >> 4, lc = lane & 15;
  const int tm = (blockIdx.y & 1) * 128, td = (blockIdx.y >> 1) * 128;
  const int m0w = (w & 1) * 64, d0w = (w >> 1) * 64;

  f32x4 acc[4][4];
  for (int i = 0; i < 4; ++i)
    for (int j = 0; j < 4; ++j) acc[i][j] = (f32x4){0.f, 0.f, 0.f, 0.f};

  for (int c = blockIdx.x; c < CHUNKS; c += KVSPLIT) {
    const long long noff = (long long)c * 64;
    for (int it = 0; it < 4; ++it) {
      int s = it * 256 + tid;
      int mloc = s >> 3, gc = s & 7, gsrc = gc ^ (mloc & 7);
      async16(&sA[s], kT + (size_t)(tm + mloc) * NPAD + noff + gsrc * 8);
      async16(&sB[s], vT + (size_t)(td + mloc) * NPAD + noff + gsrc * 8);
    }
    __syncthreads();
    for (int kk = 0; kk < 2; ++kk) {
      bf16x8 af[4], bf[4];
      for (int fr = 0; fr < 4; ++fr) {
        int m = m0w + fr * 16 + lc;
        af[fr] = __builtin_bit_cast(bf16x8, sA[m * 8 + ((kk * 4 + quad) ^ (m & 7))]);
      }
      for (int fc = 0; fc < 4; ++fc) {
        int d = d0w + fc * 16 + lc;
        bf[fc] = __builtin_bit_cast(bf16x8, sB[d * 8 + ((kk * 4 + quad) ^ (d & 7))]);
      }
      for (int fr = 0; fr < 4; ++fr)
        for (int fc = 0; fc < 4; ++fc)
          acc[fr][fc] = __builtin_amdgcn_mfma_f32_16x16x32_bf16(af[fr], bf[fc], acc[fr][fc], 0, 0, 0);
    }
    __syncthreads();
  }
  // store partial KV^T tile: part[split][d][m], float4 along m (full-line coverage)
  float* my = part + (size_t)blockIdx.x * 65536;
  for (int fr = 0; fr < 4; ++fr) {
    int m = tm + m0w + fr * 16 + quad * 4;
    for (int fc = 0; fc < 4; ++fc) {
      int d = td + d0w + fc * 16 + lc;
      *(f32x4*)(my + (size_t)d * 256 + m) = acc[fr][fc];
    }
  }
}

// ---------------- finalize: sum partials, scale by gamma, emit bf16; scale ksum --
__global__ void k_fin(const float* __restrict__ red, const float* __restrict__ part,
                      unsigned short* __restrict__ kvb, float* __restrict__ ksums) {
  float g = rsqrtf(red[0]) * rsqrtf(red[1]);   // 1/(||q|| * ||k||)
  if (blockIdx.x == 256) {
    ksums[threadIdx.x] = red[16 + threadIdx.x] * g;
    return;
  }
  int i = blockIdx.x * 256 + threadIdx.x;
  float s = 0.f;
  for (int p = 0; p < KVSPLIT; ++p) s += part[(size_t)p * 65536 + i];
  kvb[i] = f2bf(s * g);
}

// ---------------- launch ----------------
extern "C" void kernel_launch(void* const* d_in, const int* in_sizes, int n_in,
                              void* d_out, int out_size, void* d_ws, size_t ws_size,
                              hipStream_t stream) {
  const float* x   = (const float*)d_in[0];
  const float* fcw = (const float*)d_in[1];
  const float* fcb = (const float*)d_in[2];
  const float* wqw = (const float*)d_in[3];
  const float* wqb = (const float*)d_in[4];
  const float* wkw = (const float*)d_in[5];
  const float* wkb = (const float*)d_in[6];
  const float* wvw = (const float*)d_in[7];
  const float* wvb = (const float*)d_in[8];
  const float* lng = (const float*)d_in[9];
  const float* lnb = (const float*)d_in[10];
  char* ws = (char*)d_ws;
  float* out = (float*)d_out;

  unsigned short* xb  = (unsigned short*)(ws + OFF_XB);
  unsigned short* h0  = (unsigned short*)(ws + OFF_H0);
  unsigned short* h1  = xb;  // x dead after fc kernel -> reuse as h1
  unsigned short* q   = (unsigned short*)(ws + OFF_Q);
  unsigned short* kT  = (unsigned short*)(ws + OFF_KT);
  unsigned short* vT  = (unsigned short*)(ws + OFF_VT);
  unsigned short* wb  = (unsigned short*)(ws + OFF_WB);
  unsigned short* kvb = (unsigned short*)(ws + OFF_KVB);
  float* ksums = (float*)(ws + OFF_KS);
  float* part = out;  // d_out as KV-partial scratch (33.5MB <= 102MB), overwritten by final pass2

  k_zero<<<4, 256, 0, stream>>>(ws);
  k_conv<<<25448, 256, 0, stream>>>(x, fcw, wqw, wkw, wvw, ws);

  // fc: h0 = relu(LN(x @ fc_w^T + fc_b))
  gemm64<<<dim3(1563, 1, 1), 256, 0, stream>>>(
      xb, wb, fcb, nullptr, nullptr, lng, lnb,
      h0, nullptr, nullptr, nullptr, nullptr, nullptr, nullptr, nullptr, 0);

  for (int l = 0; l < 2; ++l) {
    unsigned short* hin  = (l == 0) ? h0 : h1;
    unsigned short* hout = (l == 0) ? h1 : nullptr;
    float* red = (float*)(ws + OFF_RED) + (size_t)l * REDL;

    // q,k,v + reductions (z: 0=q,1=k,2=v)
    gemm64<<<dim3(1563, 1, 3), 256, 0, stream>>>(
        hin, wb + (size_t)(1 + 3 * l) * 65536,
        wqb + l * 256, wkb + l * 256, wvb + l * 256, nullptr, nullptr,
        q, kT, vT, nullptr, nullptr, nullptr, nullptr, red, 100);

    kvker<<<dim3(KVSPLIT, 4, 1), 256, 0, stream>>>(kT, vT, part);
    k_fin<<<257, 256, 0, stream>>>(red, part, kvb, ksums);

    // pass2: attn + mix + LN + relu
    gemm64<<<dim3(1563, 1, 1), 256, 0, stream>>>(
        q, kvb, nullptr, nullptr, nullptr,
        lng + (size_t)(l + 1) * 256, lnb + (size_t)(l + 1) * 256,
        hout, nullptr, nullptr, (l == 1) ? out : nullptr,
        vT, hin, ksums, red, 4 + l);
  }
}

// Round 3
// 747.397 us; speedup vs baseline: 3.3875x; 3.0281x over previous
//
#include <hip/hip_runtime.h>

// ---------------- constants ----------------
#define NV 100000
#define NVf 100000.0f
#define NPAD 100032LL
#define CHUNKS 1563
#define NBG 48            // gpass split-K blocks (x-dim)

typedef __attribute__((ext_vector_type(8))) short bf16x8;
typedef __attribute__((ext_vector_type(4))) float f32x4;

constexpr size_t SB      = (size_t)NPAD * 256 * 2;      // one [NPAD,256] bf16
constexpr size_t OFF_XB  = 0;                           // x bf16; reused as h1
constexpr size_t OFF_H0  = SB;
constexpr size_t OFF_WB  = 2 * SB;                      // 7 x 65536 bf16 [fc,q0,k0,v0,q1,k1,v1]
constexpr size_t OFF_GBF = OFF_WB + (size_t)7 * 65536 * 2;
constexpr size_t OFF_PQ  = OFF_GBF + 131072;
constexpr size_t OFF_PK  = OFF_PQ + 131072;
constexpr size_t OFF_KVT = OFF_PK + 131072;
constexpr size_t OFF_WEF = OFF_KVT + 131072;
constexpr size_t OFF_HP  = OFF_WEF + 131072;            // 2 x 64x256 f32 colsum partials
constexpr size_t OFF_KSH = OFF_HP + 131072;             // 256 f32 (Wk hsum)
constexpr size_t OFF_VSH = OFF_KSH + 1024;              // 256 f32 (Wv hsum)
constexpr size_t OFF_U   = OFF_VSH + 1024;              // 256 f32
constexpr size_t OFF_BE  = OFF_U + 1024;                // 256 f32
constexpr size_t OFF_RED = OFF_BE + 1024;               // [0]=q_ss [1]=k_ss [2]=c

// ---------------- helpers ----------------
__device__ __forceinline__ float b2f(unsigned h) {
  unsigned u = h << 16;
  return __builtin_bit_cast(float, u);
}
__device__ __forceinline__ unsigned short f2bf(float x) {
  unsigned u = __builtin_bit_cast(unsigned, x);
  u = (u + 0x7fffu + ((u >> 16) & 1u)) >> 16;
  return (unsigned short)u;
}
__device__ __forceinline__ void async16(void* lds, const void* g) {
  __builtin_amdgcn_global_load_lds((const __attribute__((address_space(1))) unsigned*)g,
                                   (__attribute__((address_space(3))) unsigned*)lds,
                                   16, 0, 0);
}
// strided bf16 frag: elements T[nbase+i][col] from swizzled tile [rows][GRAN granules]
template <int GRAN>
__device__ __forceinline__ bf16x8 frag_strided(const uint4* t, int nbase, int col) {
  const unsigned short* sp = (const unsigned short*)t;
  bf16x8 f;
  int ch = col >> 3, cl = col & 7;
#pragma unroll
  for (int i = 0; i < 8; ++i) {
    int n = nbase + i;
    f[i] = (short)sp[(n * GRAN + ((ch ^ n) & (GRAN - 1))) * 8 + cl];
  }
  return f;
}

// ---------------- zero hpart ----------------
__global__ void k_zero(char* ws) {
  int i = blockIdx.x * 256 + threadIdx.x;
  *(float4*)((float*)(ws + OFF_HP) + (size_t)i * 4) = make_float4(0.f, 0.f, 0.f, 0.f);
}

// ---------------- convert x + weights to bf16 ----------------
__global__ void k_conv(const float* __restrict__ x, const float* __restrict__ fcw,
                       const float* __restrict__ wq, const float* __restrict__ wk,
                       const float* __restrict__ wv, char* __restrict__ ws) {
  long long t = (long long)blockIdx.x * 256 + threadIdx.x;
  if (t < 6400000LL) {
    float4 v = ((const float4*)x)[t];
    unsigned lo = (unsigned)f2bf(v.x) | ((unsigned)f2bf(v.y) << 16);
    unsigned hi = (unsigned)f2bf(v.z) | ((unsigned)f2bf(v.w) << 16);
    ((uint2*)(ws + OFF_XB))[t] = make_uint2(lo, hi);
  } else {
    long long u = t - 6400000LL;
    if (u < 114688LL) {
      int e4 = (int)(u << 2);
      int slot = e4 >> 16, within = e4 & 65535;
      const float* src;
      if (slot == 0) src = fcw + within;
      else {
        int s = slot - 1, l = s / 3, k = s % 3;
        src = (k == 0 ? wq : (k == 1 ? wk : wv)) + l * 65536 + within;
      }
      float4 v = *(const float4*)src;
      unsigned lo = (unsigned)f2bf(v.x) | ((unsigned)f2bf(v.y) << 16);
      unsigned hi = (unsigned)f2bf(v.z) | ((unsigned)f2bf(v.w) << 16);
      ((uint2*)(ws + OFF_WB))[u] = make_uint2(lo, hi);
    }
  }
}

// ---------------- main pass: C = H @ W^T-ish, epilogue fc/attn + LN + relu ------
// mode 0: fc (bias + LN + relu -> bf16);  1: attn mid (-> bf16);  2: attn final (-> f32)
__global__ __launch_bounds__(256) void outpass(
    const unsigned short* __restrict__ A,   // H [NPAD][256] bf16
    const unsigned short* __restrict__ W,   // [256 out][256 k] bf16
    const float* __restrict__ bias,
    const float* __restrict__ lng, const float* __restrict__ lnb,
    const float* __restrict__ u, const float* __restrict__ beff,
    const float* __restrict__ red,          // red[2]=c
    float* __restrict__ hpart,              // colsum partials (null for mode 2)
    unsigned short* __restrict__ outB, float* __restrict__ outF, int mode) {
  __shared__ uint4 sH4[2048];               // 32 KB: H tile [64 n][32 gran] swizzled
  __shared__ uint4 sW4[2048];               // 32 KB: W kc-tile; reused as store tile
  __shared__ float sMisc[704];

  const int tid = threadIdx.x;
  const int w = tid >> 6, lane = tid & 63, quad = lane >> 4, lc = lane & 15;
  const int c0 = w * 64;
  const long long n0 = (long long)blockIdx.x * 64;

#pragma unroll
  for (int it = 0; it < 8; ++it) {          // stage H tile once
    int s = it * 256 + tid;
    int n = s >> 5, gl = s & 31, g = gl ^ (n & 31);
    async16(&sH4[s], A + (size_t)(n0 + n) * 256 + g * 8);
  }

  f32x4 acc[4][4];
  for (int i = 0; i < 4; ++i)
    for (int j = 0; j < 4; ++j) acc[i][j] = (f32x4){0.f, 0.f, 0.f, 0.f};

  for (int kc = 0; kc < 4; ++kc) {
#pragma unroll
    for (int it = 0; it < 8; ++it) {        // stage W tile [256 j][8 gran]
      int s = it * 256 + tid;
      int j = s >> 3, gl = s & 7, g = gl ^ (j & 7);
      async16(&sW4[s], W + (size_t)j * 256 + kc * 64 + g * 8);
    }
    __syncthreads();
#pragma unroll
    for (int kk = 0; kk < 2; ++kk) {
      bf16x8 af[4], bv[4];
      for (int fr = 0; fr < 4; ++fr) {
        int m = fr * 16 + lc;
        af[fr] = __builtin_bit_cast(bf16x8, sH4[m * 32 + (((kc * 8 + kk * 4 + quad) ^ m) & 31)]);
      }
      for (int fc = 0; fc < 4; ++fc) {
        int j = c0 + fc * 16 + lc;
        bv[fc] = __builtin_bit_cast(bf16x8, sW4[j * 8 + (((kk * 4 + quad) ^ j) & 7)]);
      }
      for (int fr = 0; fr < 4; ++fr)
        for (int fc = 0; fc < 4; ++fc)
          acc[fr][fc] = __builtin_amdgcn_mfma_f32_16x16x32_bf16(af[fr], bv[fc], acc[fr][fc], 0, 0, 0);
    }
    __syncthreads();
  }

  const bool attn = (mode != 0);
  if (attn) {                                // rowdot h.u
    int row = tid >> 2, p = tid & 3;
    float rd = 0.f;
    const float4* u4 = (const float4*)u;
#pragma unroll
    for (int g8 = 0; g8 < 8; ++g8) {
      int g = p * 8 + g8;
      uint4 hv = sH4[row * 32 + ((g ^ row) & 31)];
      float4 ua = u4[g * 2], ub = u4[g * 2 + 1];
      rd += b2f(hv.x & 0xffffu) * ua.x + b2f(hv.x >> 16) * ua.y
          + b2f(hv.y & 0xffffu) * ua.z + b2f(hv.y >> 16) * ua.w
          + b2f(hv.z & 0xffffu) * ub.x + b2f(hv.z >> 16) * ub.y
          + b2f(hv.w & 0xffffu) * ub.z + b2f(hv.w >> 16) * ub.w;
    }
    sMisc[tid] = rd;
  }
  __syncthreads();
  if (attn && tid < 64) {
    float s = sMisc[tid * 4] + sMisc[tid * 4 + 1] + sMisc[tid * 4 + 2] + sMisc[tid * 4 + 3];
    sMisc[640 + tid] = 1.0f / (s + red[2]);
  }
  __syncthreads();

  float gv[4], bb[4], be[4], bq[4];
  for (int fc = 0; fc < 4; ++fc) {
    int j = c0 + fc * 16 + lc;
    gv[fc] = lng[j]; bb[fc] = lnb[j];
    if (attn) be[fc] = beff[j]; else bq[fc] = bias[j];
  }

  // pass1: mix/bias + LN stats
  for (int fr = 0; fr < 4; ++fr) {
    int rrb = fr * 16 + quad * 4;
    float s1[4] = {0, 0, 0, 0}, s2[4] = {0, 0, 0, 0};
    for (int fc = 0; fc < 4; ++fc) {
      int j = c0 + fc * 16 + lc;
      for (int r = 0; r < 4; ++r) {
        int m = rrb + r;
        float v = acc[fr][fc][r];
        if (attn) {
          float hm = b2f(((const unsigned short*)sH4)[(m * 32 + (((j >> 3) ^ m) & 31)) * 8 + (j & 7)]);
          v = 0.5f * ((v + be[fc]) * sMisc[640 + m]) + 0.5f * hm;
        } else v += bq[fc];
        acc[fr][fc][r] = v;
        s1[r] += v; s2[r] += v * v;
      }
    }
    for (int r = 0; r < 4; ++r) {
      float a = s1[r], b = s2[r];
      a += __shfl_xor(a, 1); b += __shfl_xor(b, 1);
      a += __shfl_xor(a, 2); b += __shfl_xor(b, 2);
      a += __shfl_xor(a, 4); b += __shfl_xor(b, 4);
      a += __shfl_xor(a, 8); b += __shfl_xor(b, 8);
      if (lc == 0) { sMisc[w * 64 + rrb + r] = a; sMisc[256 + w * 64 + rrb + r] = b; }
    }
  }
  __syncthreads();
  if (tid < 64) {
    float S = sMisc[tid] + sMisc[64 + tid] + sMisc[128 + tid] + sMisc[192 + tid];
    float Q = sMisc[256 + tid] + sMisc[320 + tid] + sMisc[384 + tid] + sMisc[448 + tid];
    float mean = S * (1.f / 256.f);
    float var = Q * (1.f / 256.f) - mean * mean;
    sMisc[512 + tid] = mean; sMisc[576 + tid] = rsqrtf(var + 1e-5f);
  }
  __syncthreads();

  if (mode < 2) {
    float cs[4] = {0, 0, 0, 0};
    unsigned short* sT = (unsigned short*)sW4;
    for (int fr = 0; fr < 4; ++fr)
      for (int fc = 0; fc < 4; ++fc) {
        int j = c0 + fc * 16 + lc;
        for (int r = 0; r < 4; ++r) {
          int m = fr * 16 + quad * 4 + r;
          float y = (acc[fr][fc][r] - sMisc[512 + m]) * sMisc[576 + m] * gv[fc] + bb[fc];
          y = fmaxf(y, 0.f);
          if (n0 + m >= NV) y = 0.f;           // zero pads (G-pass reads them)
          cs[fc] += y;
          sT[(m * 32 + (((j >> 3) ^ m) & 31)) * 8 + (j & 7)] = f2bf(y);
        }
      }
    __syncthreads();
    {
      int row = tid >> 2;
      uint4* dst = (uint4*)(outB + (size_t)(n0 + row) * 256);
#pragma unroll
      for (int i = 0; i < 8; ++i) {           // lanes 0-3 cover a full 64B line
        int g = i * 4 + (tid & 3);
        dst[g] = sW4[row * 32 + ((g ^ row) & 31)];
      }
    }
    for (int fc = 0; fc < 4; ++fc) {          // colsum -> hpart (next layer's hsum)
      float c = cs[fc];
      c += __shfl_xor(c, 16); c += __shfl_xor(c, 32);
      if (quad == 0) atomicAdd(&hpart[(blockIdx.x & 63) * 256 + c0 + fc * 16 + lc], c);
    }
  } else {
    float* sTf = (float*)sW4;
    for (int hh = 0; hh < 2; ++hh) {
      if (hh) __syncthreads();
      for (int fr = hh * 2; fr < hh * 2 + 2; ++fr)
        for (int fc = 0; fc < 4; ++fc) {
          int j = c0 + fc * 16 + lc;
          for (int r = 0; r < 4; ++r) {
            int m = fr * 16 + quad * 4 + r, r32 = m - hh * 32;
            float y = (acc[fr][fc][r] - sMisc[512 + m]) * sMisc[576 + m] * gv[fc] + bb[fc];
            y = fmaxf(y, 0.f);
            sTf[(r32 * 64 + (((j >> 2) ^ r32) & 63)) * 4 + (j & 3)] = y;
          }
        }
      __syncthreads();
      int row32 = tid >> 3;
      long long n = n0 + hh * 32 + row32;
      if (n < NV) {
        uint4* dst = (uint4*)(outF + n * 256);
#pragma unroll
        for (int i = 0; i < 8; ++i) {         // lanes 0-7 cover 128B contiguous
          int g = i * 8 + (tid & 7);
          dst[g] = sW4[row32 * 64 + ((g ^ row32) & 63)];
        }
      }
    }
  }
}

// ---------------- G-pass: partial G = H^T H, quadrant split ----------------
__global__ __launch_bounds__(256) void gpass(const unsigned short* __restrict__ H,
                                             float* __restrict__ gpart) {
  __shared__ uint4 sHa4[1024], sHb4[1024];    // [64 n][16 gran] each
  const int tid = threadIdx.x;
  const int w = tid >> 6, lane = tid & 63, quad = lane >> 4, lc = lane & 15;
  const int qm = blockIdx.y & 1, qj = blockIdx.y >> 1;
  const int mw = (w & 1) * 64, jw = (w >> 1) * 64;

  f32x4 acc[4][4];
  for (int i = 0; i < 4; ++i)
    for (int j = 0; j < 4; ++j) acc[i][j] = (f32x4){0.f, 0.f, 0.f, 0.f};

  for (int c = blockIdx.x; c < CHUNKS; c += NBG) {
#pragma unroll
    for (int it = 0; it < 4; ++it) {
      int s = it * 256 + tid;
      int n = s >> 4, gl = s & 15, g = gl ^ (n & 15);
      const unsigned short* rowp = H + ((size_t)c * 64 + n) * 256;
      async16(&sHa4[s], rowp + qm * 128 + g * 8);
      async16(&sHb4[s], rowp + qj * 128 + g * 8);
    }
    __syncthreads();
#pragma unroll
    for (int kk = 0; kk < 2; ++kk) {
      bf16x8 af[4], bv[4];
      for (int fr = 0; fr < 4; ++fr)
        af[fr] = frag_strided<16>(sHa4, kk * 32 + quad * 8, mw + fr * 16 + lc);
      for (int jf = 0; jf < 4; ++jf)
        bv[jf] = frag_strided<16>(sHb4, kk * 32 + quad * 8, jw + jf * 16 + lc);
      for (int fr = 0; fr < 4; ++fr)
        for (int jf = 0; jf < 4; ++jf)
          acc[fr][jf] = __builtin_amdgcn_mfma_f32_16x16x32_bf16(af[fr], bv[jf], acc[fr][jf], 0, 0, 0);
    }
    __syncthreads();
  }
  float* gp = gpart + (size_t)blockIdx.x * 65536;
  for (int fr = 0; fr < 4; ++fr)
    for (int jf = 0; jf < 4; ++jf) {
      int row = qm * 128 + mw + fr * 16 + quad * 4;
      int col = qj * 128 + jw + jf * 16 + lc;
      for (int r = 0; r < 4; ++r)             // 16 lanes x 4B = full 64B line / instr
        gp[(size_t)(row + r) * 256 + col] = acc[fr][jf][r];
    }
}

// ---------------- S0: reduce G partials -> Gbf; hsum; matvecs; trace biases ----
__global__ __launch_bounds__(256) void s0ker(
    const float* __restrict__ gpart, const float* __restrict__ hpart,
    const unsigned short* __restrict__ wq, const unsigned short* __restrict__ wk,
    const unsigned short* __restrict__ wv,
    const float* __restrict__ bq, const float* __restrict__ bk,
    unsigned short* __restrict__ Gbf, float* __restrict__ ksh0, float* __restrict__ vsh0,
    float* __restrict__ red) {
  const int tid = threadIdx.x;
  if (blockIdx.x < 64) {
    size_t idx = ((size_t)blockIdx.x * 256 + tid) * 4;
    float a = 0, b = 0, c = 0, d = 0;
    for (int p = 0; p < NBG; ++p) {
      float4 v = *(const float4*)(gpart + (size_t)p * 65536 + idx);
      a += v.x; b += v.y; c += v.z; d += v.w;
    }
    unsigned lo = (unsigned)f2bf(a) | ((unsigned)f2bf(b) << 16);
    unsigned hi = (unsigned)f2bf(c) | ((unsigned)f2bf(d) << 16);
    *(uint2*)(Gbf + idx) = make_uint2(lo, hi);
    return;
  }
  __shared__ float sH[256], sA[256], sBv[256];
  float hs = 0;
  for (int r = 0; r < 64; ++r) hs += hpart[r * 256 + tid];
  sH[tid] = hs;
  __syncthreads();
  float sk = 0, sv = 0, sq = 0;
  for (int g = 0; g < 32; ++g) {
    uint4 wk4 = *(const uint4*)(wk + (size_t)tid * 256 + g * 8);
    uint4 wv4 = *(const uint4*)(wv + (size_t)tid * 256 + g * 8);
    uint4 wq4 = *(const uint4*)(wq + (size_t)tid * 256 + g * 8);
    unsigned uk[4] = {wk4.x, wk4.y, wk4.z, wk4.w};
    unsigned uv[4] = {wv4.x, wv4.y, wv4.z, wv4.w};
    unsigned uq[4] = {wq4.x, wq4.y, wq4.z, wq4.w};
    for (int h = 0; h < 4; ++h) {
      float h0 = sH[g * 8 + h * 2], h1 = sH[g * 8 + h * 2 + 1];
      sk += b2f(uk[h] & 0xffffu) * h0 + b2f(uk[h] >> 16) * h1;
      sv += b2f(uv[h] & 0xffffu) * h0 + b2f(uv[h] >> 16) * h1;
      sq += b2f(uq[h] & 0xffffu) * h0 + b2f(uq[h] >> 16) * h1;
    }
  }
  ksh0[tid] = sk; vsh0[tid] = sv;
  sA[tid]  = 2.f * bq[tid] * sq + NVf * bq[tid] * bq[tid];
  sBv[tid] = 2.f * bk[tid] * sk + NVf * bk[tid] * bk[tid];
  __syncthreads();
  if (tid == 0) {
    float a = 0, b = 0;
    for (int i = 0; i < 256; ++i) { a += sA[i]; b += sBv[i]; }
    red[0] = a; red[1] = b;
  }
}

// ---------------- small GEMMs: S1 (Pq,Pk + traces) / S2 (KVT + rank1) ----------
__global__ __launch_bounds__(256) void ks12(
    const unsigned short* __restrict__ A0, const unsigned short* __restrict__ A1,
    const unsigned short* __restrict__ B,
    unsigned short* __restrict__ O0, unsigned short* __restrict__ O1,
    const float* __restrict__ ksh0, const float* __restrict__ vsh0,
    const float* __restrict__ bk, const float* __restrict__ bv,
    float* __restrict__ red, int mode) {
  __shared__ uint4 sA4[512], sB4[2048];
  __shared__ float sRd[4];
  const int tid = threadIdx.x;
  const int w = tid >> 6, lane = tid & 63, quad = lane >> 4, lc = lane & 15;
  const int c0 = w * 64;
  const int mat = (mode == 2) ? 0 : (blockIdx.x >> 2);
  const int mt  = (mode == 2) ? blockIdx.x : (blockIdx.x & 3);
  const unsigned short* A = mat ? A1 : A0;
  unsigned short* O = mat ? O1 : O0;

  f32x4 acc[4][4];
  for (int i = 0; i < 4; ++i)
    for (int j = 0; j < 4; ++j) acc[i][j] = (f32x4){0.f, 0.f, 0.f, 0.f};

  for (int kc = 0; kc < 4; ++kc) {
#pragma unroll
    for (int it = 0; it < 2; ++it) {
      int s = it * 256 + tid;
      int m = s >> 3, gl = s & 7, g = gl ^ (m & 7);
      async16(&sA4[s], A + (size_t)(mt * 64 + m) * 256 + kc * 64 + g * 8);
    }
#pragma unroll
    for (int it = 0; it < 8; ++it) {
      int s = it * 256 + tid;
      int j = s >> 3, gl = s & 7, g = gl ^ (j & 7);
      async16(&sB4[s], B + (size_t)j * 256 + kc * 64 + g * 8);
    }
    __syncthreads();
#pragma unroll
    for (int kk = 0; kk < 2; ++kk) {
      bf16x8 af[4], bv4[4];
      for (int fr = 0; fr < 4; ++fr) {
        int m = fr * 16 + lc;
        af[fr] = __builtin_bit_cast(bf16x8, sA4[m * 8 + (((kk * 4 + quad) ^ m) & 7)]);
      }
      for (int fc = 0; fc < 4; ++fc) {
        int j = c0 + fc * 16 + lc;
        bv4[fc] = __builtin_bit_cast(bf16x8, sB4[j * 8 + (((kk * 4 + quad) ^ j) & 7)]);
      }
      for (int fr = 0; fr < 4; ++fr)
        for (int fc = 0; fc < 4; ++fc)
          acc[fr][fc] = __builtin_amdgcn_mfma_f32_16x16x32_bf16(af[fr], bv4[fc], acc[fr][fc], 0, 0, 0);
    }
    __syncthreads();
  }

  unsigned short* sT = (unsigned short*)sB4;
  if (mode != 2) {
    float tr = 0.f;
    for (int fr = 0; fr < 4; ++fr)
      for (int fc = 0; fc < 4; ++fc) {
        int j = c0 + fc * 16 + lc;
        for (int r = 0; r < 4; ++r) {
          int mL = fr * 16 + quad * 4 + r;
          float v = acc[fr][fc][r];
          tr += v * b2f(A[(size_t)(mt * 64 + mL) * 256 + j]);
          sT[(mL * 32 + (((j >> 3) ^ mL) & 31)) * 8 + (j & 7)] = f2bf(v);
        }
      }
    for (int msk = 1; msk <= 32; msk <<= 1) tr += __shfl_xor(tr, msk);
    if (lane == 0) sRd[w] = tr;
    __syncthreads();
    int row = tid >> 2;
    uint4* dst = (uint4*)(O + (size_t)(mt * 64 + row) * 256);
#pragma unroll
    for (int i = 0; i < 8; ++i) {
      int g = i * 4 + (tid & 3);
      dst[g] = sB4[row * 32 + ((g ^ row) & 31)];
    }
    if (tid == 0) atomicAdd(&red[mat], sRd[0] + sRd[1] + sRd[2] + sRd[3]);
  } else {
    for (int fr = 0; fr < 4; ++fr)
      for (int fc = 0; fc < 4; ++fc) {
        int d = c0 + fc * 16 + lc;
        for (int r = 0; r < 4; ++r) {
          int mL = fr * 16 + quad * 4 + r, mrow = mt * 64 + mL;
          float v = acc[fr][fc][r] + ksh0[mrow] * bv[d] + bk[mrow] * (vsh0[d] + NVf * bv[d]);
          sT[(d * 8 + (((mL >> 3) ^ d) & 7)) * 8 + (mL & 7)] = f2bf(v);
        }
      }
    __syncthreads();
    for (int p = 0; p < 4; ++p) {
      int d = p * 64 + (tid >> 2);
#pragma unroll
      for (int i = 0; i < 2; ++i) {
        int g = i * 4 + (tid & 3);
        *(uint4*)(O0 + (size_t)d * 256 + mt * 64 + g * 8) = sB4[d * 8 + ((g ^ d) & 7)];
      }
    }
  }
}

// ---------------- S3: Weff^T = gamma*KVT*Wq + N*Wv; vectors u, beff, c ---------
__global__ __launch_bounds__(256) void ks3(
    const unsigned short* __restrict__ KVT, const unsigned short* __restrict__ wq,
    const unsigned short* __restrict__ wv,
    const float* __restrict__ ksh0,
    const float* __restrict__ bq, const float* __restrict__ bk, const float* __restrict__ bv,
    unsigned short* __restrict__ Wef, float* __restrict__ uvec, float* __restrict__ bev,
    float* __restrict__ red) {
  const int tid = threadIdx.x;
  if (blockIdx.x == 4) {
    __shared__ float sV[256], sC[256];
    float gam = rsqrtf(red[0]) * rsqrtf(red[1]);
    sV[tid] = ksh0[tid] + NVf * bk[tid];
    __syncthreads();
    float s = 0;
    for (int m = 0; m < 256; ++m) s += b2f(wq[(size_t)m * 256 + tid]) * sV[m];
    uvec[tid] = gam * s;
    float s2 = 0;
    const uint4* kr = (const uint4*)(KVT + (size_t)tid * 256);
    for (int g = 0; g < 32; ++g) {
      uint4 v = kr[g];
      unsigned uu[4] = {v.x, v.y, v.z, v.w};
      for (int h = 0; h < 4; ++h) {
        s2 += b2f(uu[h] & 0xffffu) * bq[g * 8 + h * 2] + b2f(uu[h] >> 16) * bq[g * 8 + h * 2 + 1];
      }
    }
    bev[tid] = gam * s2 + NVf * bv[tid];
    sC[tid] = bq[tid] * sV[tid];
    __syncthreads();
    if (tid == 0) {
      float t = 0;
      for (int i = 0; i < 256; ++i) t += sC[i];
      red[2] = gam * t + NVf;
    }
    return;
  }
  __shared__ uint4 sA4[2048], sB4[2048];
  const int w = tid >> 6, lane = tid & 63, quad = lane >> 4, lc = lane & 15;
  const int c0 = w * 64, dt = blockIdx.x;
#pragma unroll
  for (int it = 0; it < 8; ++it) {            // KVT slab [64 d][32 gran], staged once
    int s = it * 256 + tid;
    int n = s >> 5, gl = s & 31, g = gl ^ (n & 31);
    async16(&sA4[s], KVT + (size_t)(dt * 64 + n) * 256 + g * 8);
  }
  f32x4 acc[4][4];
  for (int i = 0; i < 4; ++i)
    for (int j = 0; j < 4; ++j) acc[i][j] = (f32x4){0.f, 0.f, 0.f, 0.f};
  for (int kc = 0; kc < 4; ++kc) {
#pragma unroll
    for (int it = 0; it < 8; ++it) {          // Wq k-chunk [64 m][32 gran]
      int s = it * 256 + tid;
      int n = s >> 5, gl = s & 31, g = gl ^ (n & 31);
      async16(&sB4[s], wq + (size_t)(kc * 64 + n) * 256 + g * 8);
    }
    __syncthreads();
#pragma unroll
    for (int kk = 0; kk < 2; ++kk) {
      bf16x8 af[4], bv4[4];
      for (int fr = 0; fr < 4; ++fr) {
        int dL = fr * 16 + lc;
        af[fr] = __builtin_bit_cast(bf16x8, sA4[dL * 32 + (((kc * 8 + kk * 4 + quad) ^ dL) & 31)]);
      }
      for (int fc = 0; fc < 4; ++fc)
        bv4[fc] = frag_strided<32>(sB4, kk * 32 + quad * 8, c0 + fc * 16 + lc);
      for (int fr = 0; fr < 4; ++fr)
        for (int fc = 0; fc < 4; ++fc)
          acc[fr][fc] = __builtin_amdgcn_mfma_f32_16x16x32_bf16(af[fr], bv4[fc], acc[fr][fc], 0, 0, 0);
    }
    __syncthreads();
  }
  float gam = rsqrtf(red[0]) * rsqrtf(red[1]);
  unsigned short* sT = (unsigned short*)sB4;
  for (int fr = 0; fr < 4; ++fr)
    for (int fc = 0; fc < 4; ++fc) {
      int a = c0 + fc * 16 + lc;
      for (int r = 0; r < 4; ++r) {
        int dL = fr * 16 + quad * 4 + r;
        float v = gam * acc[fr][fc][r] + NVf * b2f(wv[(size_t)(dt * 64 + dL) * 256 + a]);
        sT[(dL * 32 + (((a >> 3) ^ dL) & 31)) * 8 + (a & 7)] = f2bf(v);
      }
    }
  __syncthreads();
  int row = tid >> 2;
  uint4* dst = (uint4*)(Wef + (size_t)(dt * 64 + row) * 256);
#pragma unroll
  for (int i = 0; i < 8; ++i) {
    int g = i * 4 + (tid & 3);
    dst[g] = sB4[row * 32 + ((g ^ row) & 31)];
  }
}

// ---------------- launch ----------------
extern "C" void kernel_launch(void* const* d_in, const int* in_sizes, int n_in,
                              void* d_out, int out_size, void* d_ws, size_t ws_size,
                              hipStream_t stream) {
  const float* x   = (const float*)d_in[0];
  const float* fcw = (const float*)d_in[1];
  const float* fcb = (const float*)d_in[2];
  const float* wqw = (const float*)d_in[3];
  const float* wqb = (const float*)d_in[4];
  const float* wkw = (const float*)d_in[5];
  const float* wkb = (const float*)d_in[6];
  const float* wvw = (const float*)d_in[7];
  const float* wvb = (const float*)d_in[8];
  const float* lng = (const float*)d_in[9];
  const float* lnb = (const float*)d_in[10];
  char* ws = (char*)d_ws;
  float* out = (float*)d_out;

  unsigned short* xb  = (unsigned short*)(ws + OFF_XB);
  unsigned short* h0  = (unsigned short*)(ws + OFF_H0);
  unsigned short* h1  = xb;                   // x dead after fc -> reuse
  unsigned short* wb  = (unsigned short*)(ws + OFF_WB);
  unsigned short* Gbf = (unsigned short*)(ws + OFF_GBF);
  unsigned short* Pq  = (unsigned short*)(ws + OFF_PQ);
  unsigned short* Pk  = (unsigned short*)(ws + OFF_PK);
  unsigned short* KVT = (unsigned short*)(ws + OFF_KVT);
  unsigned short* Wef = (unsigned short*)(ws + OFF_WEF);
  float* hp   = (float*)(ws + OFF_HP);
  float* kshv = (float*)(ws + OFF_KSH);
  float* vshv = (float*)(ws + OFF_VSH);
  float* uvec = (float*)(ws + OFF_U);
  float* bev  = (float*)(ws + OFF_BE);
  float* red  = (float*)(ws + OFF_RED);
  float* gpart = out;                         // d_out as G-partial scratch (12.6MB)

  k_zero<<<32, 256, 0, stream>>>(ws);
  k_conv<<<25448, 256, 0, stream>>>(x, fcw, wqw, wkw, wvw, ws);

  // fc: h0 = relu(LN(x @ fc_w^T + fc_b)), colsums -> hp[0]
  outpass<<<1563, 256, 0, stream>>>(xb, wb, fcb, lng, lnb,
                                    nullptr, nullptr, nullptr, hp, h0, nullptr, 0);

  for (int l = 0; l < 2; ++l) {
    const unsigned short* wq = wb + (size_t)(1 + 3 * l) * 65536;
    const unsigned short* wk = wq + 65536;
    const unsigned short* wv = wk + 65536;
    const float* bq = wqb + l * 256;
    const float* bk = wkb + l * 256;
    const float* bv = wvb + l * 256;
    unsigned short* hin = l ? h1 : h0;
    float* hpIn = hp + (size_t)l * 16384;

    gpass<<<dim3(NBG, 4), 256, 0, stream>>>(hin, gpart);
    s0ker<<<65, 256, 0, stream>>>(gpart, hpIn, wq, wk, wv, bq, bk, Gbf, kshv, vshv, red);
    ks12<<<8, 256, 0, stream>>>(wq, wk, Gbf, Pq, Pk, nullptr, nullptr, nullptr, nullptr, red, 0);
    ks12<<<4, 256, 0, stream>>>(Pk, nullptr, wv, KVT, nullptr, kshv, vshv, bk, bv, red, 2);
    ks3<<<5, 256, 0, stream>>>(KVT, wq, wv, kshv, bq, bk, bv, Wef, uvec, bev, red);

    outpass<<<1563, 256, 0, stream>>>(hin, Wef, nullptr,
                                      lng + (size_t)(l + 1) * 256, lnb + (size_t)(l + 1) * 256,
                                      uvec, bev, red,
                                      (l == 0) ? (hp + 16384) : nullptr,
                                      (l == 0) ? h1 : nullptr,
                                      (l == 1) ? out : nullptr, l + 1);
  }
}